// Round 3
// baseline (270.722 us; speedup 1.0000x reference)
//
#include <hip/hip_runtime.h>
#include <hip/hip_bf16.h>

#define BB 16
#define NN 4096
#define DD 64
#define NM1 4095
#define BM 64
#define BK 64
#define LDX 72   // padded LDS row stride (bf16 elems); 144B, keeps 16B align

typedef __bf16 bf16x8 __attribute__((ext_vector_type(8)));
typedef float f32x4 __attribute__((ext_vector_type(4)));

// XOR-swizzle of k-octets by (d>>3): spreads transposed scalar LDS writes
#define SWZ(k, d) (((((k) >> 3) ^ (((d) >> 3) & 7)) << 3) | ((k) & 7))

// ---------------------------------------------------------------------------
// Kernel 1: incidence_all = scatter(mask(inc)) + I  (f32 in, f32 out)
//           comb[i] = l1[i] + 0.001*l2[i]  -> 16KB ws
// ---------------------------------------------------------------------------
__global__ __launch_bounds__(256) void build_kernel(
    const float* __restrict__ inc, float* __restrict__ out_inc,
    float* __restrict__ comb)
{
    int i = blockIdx.x;
    int t = threadIdx.x;
    const float* row = inc + (size_t)i * NM1;
    float* orow = out_inc + (size_t)i * NN;
    float mx = 0.f, ss = 0.f;
    #pragma unroll
    for (int it = 0; it < 2; ++it) {
        int j0 = (it * 256 + t) * 8;
        f32x4 v0, v1;
        #pragma unroll
        for (int j = 0; j < 8; ++j) {
            int jj = j0 + j;
            float w;
            if (jj == i) {
                w = 1.0f;                         // diagonal of W + I
            } else {
                int c = jj - (jj > i);            // inverse of scatter col map
                float x = row[c];
                w = x > 0.01f ? x : 0.f;          // keep only > lb_th
                mx = fmaxf(mx, w);
                ss += w * w;
            }
            if (j < 4) v0[j] = w; else v1[j - 4] = w;
        }
        *(f32x4*)(orow + j0) = v0;
        *(f32x4*)(orow + j0 + 4) = v1;
    }
    #pragma unroll
    for (int off = 32; off; off >>= 1) {
        mx = fmaxf(mx, __shfl_down(mx, off));
        ss += __shfl_down(ss, off);
    }
    __shared__ float smx[4], sss[4];
    int wid = t >> 6, lane = t & 63;
    if (lane == 0) { smx[wid] = mx; sss[wid] = ss; }
    __syncthreads();
    if (t == 0) {
        mx = fmaxf(fmaxf(smx[0], smx[1]), fmaxf(smx[2], smx[3]));
        ss = sss[0] + sss[1] + sss[2] + sss[3];
        comb[i] = mx + 0.001f * sqrtf(ss);
    }
}

// ---------------------------------------------------------------------------
// Kernel 2: acc = (W+I) @ X  (bf16 MFMA, f32 sources converted in staging),
//           fused xp = X @ (r+I) and loss epilogue.
//   grid (NN/BM, BB/2); 256 thr / 4 waves. Wave w: rows (w&1)*32..+31 of the
//   64-row m-tile, batch half w>>1 of the 2-batch pair.
//   xp - acc = X_proj - recon.
// ---------------------------------------------------------------------------
__global__ __launch_bounds__(256) void gemm_loss_kernel(
    const float* __restrict__ A,      // [N][N] incidence_all (from kernel 1)
    const float* __restrict__ X,      // [B][N][D] f32
    const float* __restrict__ rproj,  // [D][D] f32
    const float* __restrict__ comb,   // [N]  l1 + 0.001*l2
    float* __restrict__ loss)         // [B][N] f32
{
    __shared__ __bf16 lds[(BM + 2 * DD) * LDX];   // 27648 B
    __bf16* As  = lds;                  // [64][LDX]  A tile (bf16), natural
    __bf16* Xs0 = lds + BM * LDX;       // [64][LDX]  X^T tile b0, swizzled
    __bf16* Xs1 = lds + (BM + DD) * LDX;

    int t = threadIdx.x;
    int wave = t >> 6;
    int lane = t & 63;
    int quad = lane >> 4;
    int ln   = lane & 15;
    int m0 = blockIdx.x * BM;
    int bp = blockIdx.y;
    int rowoff = (wave & 1) * 32;
    int bh = wave >> 1;
    int b  = bp * 2 + bh;

    const float* Aptr = A + (size_t)m0 * NN;
    const float* Xp0 = X + (size_t)(bp * 2) * NN * DD;
    const float* Xp1 = X + (size_t)(bp * 2 + 1) * NN * DD;

    f32x4 acc[2][4];
    f32x4 zero = {0.f, 0.f, 0.f, 0.f};
    #pragma unroll
    for (int mt = 0; mt < 2; ++mt)
        #pragma unroll
        for (int nt = 0; nt < 4; ++nt) acc[mt][nt] = zero;

    for (int kt = 0; kt < NN / BK; ++kt) {
        int k0 = kt * BK;
        // A tile: 64x64 f32 -> bf16 LDS, natural layout (k contiguous)
        #pragma unroll
        for (int it = 0; it < 2; ++it) {
            int lin = it * 256 + t;
            int rr = lin >> 3;
            int o  = lin & 7;
            const float* src = Aptr + (size_t)rr * NN + k0 + o * 8;
            f32x4 u0 = *(const f32x4*)src;
            f32x4 u1 = *(const f32x4*)(src + 4);
            bf16x8 v;
            #pragma unroll
            for (int j = 0; j < 4; ++j) { v[j] = (__bf16)u0[j]; v[j + 4] = (__bf16)u1[j]; }
            *(bf16x8*)&As[rr * LDX + o * 8] = v;
        }
        // X tile: transposing scatter, f32 source. lane=(k_lo<<3)|d0 ->
        // 2KB contiguous global read per wave; 8 swizzled scalar LDS writes
        #pragma unroll
        for (int it = 0; it < 4; ++it) {
            const float* Xb = (it < 2) ? Xp0 : Xp1;
            __bf16* Xsb = (it < 2) ? Xs0 : Xs1;
            int klo = (it & 1) * 32 + wave * 8 + (lane >> 3);
            int d0  = lane & 7;
            const float* src = Xb + (size_t)(k0 + klo) * DD + d0 * 8;
            f32x4 u0 = *(const f32x4*)src;
            f32x4 u1 = *(const f32x4*)(src + 4);
            #pragma unroll
            for (int j = 0; j < 8; ++j) {
                int d = d0 * 8 + j;
                float f = (j < 4) ? u0[j] : u1[j - 4];
                Xsb[d * LDX + SWZ(klo, d)] = (__bf16)f;
            }
        }
        __syncthreads();
        const __bf16* Xsb = bh ? Xs1 : Xs0;
        #pragma unroll
        for (int kk = 0; kk < BK; kk += 32) {
            bf16x8 af[2], bfr[4];
            #pragma unroll
            for (int mt = 0; mt < 2; ++mt)
                af[mt] = *(const bf16x8*)&As[(rowoff + mt * 16 + ln) * LDX + kk + quad * 8];
            int oc = (kk >> 3) + quad;
            #pragma unroll
            for (int nt = 0; nt < 4; ++nt) {
                int n = nt * 16 + ln;
                bfr[nt] = *(const bf16x8*)&Xsb[n * LDX + ((oc ^ (n >> 3)) << 3)];
            }
            #pragma unroll
            for (int mt = 0; mt < 2; ++mt)
                #pragma unroll
                for (int nt = 0; nt < 4; ++nt)
                    acc[mt][nt] = __builtin_amdgcn_mfma_f32_16x16x32_bf16(
                        af[mt], bfr[nt], acc[mt][nt], 0, 0, 0);
        }
        __syncthreads();
    }

    // ---- phase 2: xp = Xrows @ (r + I), same C/D layout as acc ----
    __bf16* Bs  = lds;                  // alias As: [64][LDX] (r+I)^T swizzled
    __bf16* XA0 = lds + BM * LDX;       // alias Xs0: X rows b0, natural
    __bf16* XA1 = lds + (BM + DD) * LDX;
    #pragma unroll
    for (int it = 0; it < 4; ++it) {
        int lin = it * 256 + t;                 // 0..1023
        const float* Xb = (lin < 512) ? Xp0 : Xp1;
        __bf16* XA = (lin < 512) ? XA0 : XA1;
        int rr = (lin >> 3) & 63;
        int o  = lin & 7;
        const float* src = Xb + (size_t)(m0 + rr) * DD + o * 8;
        f32x4 u0 = *(const f32x4*)src;
        f32x4 u1 = *(const f32x4*)(src + 4);
        bf16x8 v;
        #pragma unroll
        for (int j = 0; j < 4; ++j) { v[j] = (__bf16)u0[j]; v[j + 4] = (__bf16)u1[j]; }
        *(bf16x8*)&XA[rr * LDX + o * 8] = v;
    }
    #pragma unroll
    for (int it = 0; it < 2; ++it) {
        int lin = it * 256 + t;                 // 0..511
        int e  = lin >> 3;
        int d0 = lin & 7;
        const float* src = rproj + (size_t)e * DD + d0 * 8;
        f32x4 u0 = *(const f32x4*)src;
        f32x4 u1 = *(const f32x4*)(src + 4);
        #pragma unroll
        for (int j = 0; j < 8; ++j) {
            int d = d0 * 8 + j;
            float f = ((j < 4) ? u0[j] : u1[j - 4]) + (d == e ? 1.0f : 0.0f);
            Bs[d * LDX + SWZ(e, d)] = (__bf16)f;
        }
    }
    __syncthreads();

    f32x4 xp[2][4];
    #pragma unroll
    for (int mt = 0; mt < 2; ++mt)
        #pragma unroll
        for (int nt = 0; nt < 4; ++nt) xp[mt][nt] = zero;
    const __bf16* XA = bh ? XA1 : XA0;
    #pragma unroll
    for (int kk = 0; kk < DD; kk += 32) {
        bf16x8 af[2], bfr[4];
        #pragma unroll
        for (int mt = 0; mt < 2; ++mt)
            af[mt] = *(const bf16x8*)&XA[(rowoff + mt * 16 + ln) * LDX + kk + quad * 8];
        int oc = (kk >> 3) + quad;
        #pragma unroll
        for (int nt = 0; nt < 4; ++nt) {
            int n = nt * 16 + ln;
            bfr[nt] = *(const bf16x8*)&Bs[n * LDX + ((oc ^ (n >> 3)) << 3)];
        }
        #pragma unroll
        for (int mt = 0; mt < 2; ++mt)
            #pragma unroll
            for (int nt = 0; nt < 4; ++nt)
                xp[mt][nt] = __builtin_amdgcn_mfma_f32_16x16x32_bf16(
                    af[mt], bfr[nt], xp[mt][nt], 0, 0, 0);
    }

    // ---- epilogue: loss = 0.2*||xp - acc|| + comb  (f32 store) ----
    // C/D layout: col = lane&15 (d), row = quad*4 + reg
    #pragma unroll
    for (int mt = 0; mt < 2; ++mt) {
        #pragma unroll
        for (int rg = 0; rg < 4; ++rg) {
            int row = m0 + rowoff + mt * 16 + quad * 4 + rg;
            float s = 0.f;
            #pragma unroll
            for (int nt = 0; nt < 4; ++nt) {
                float df = xp[mt][nt][rg] - acc[mt][nt][rg];
                s += df * df;
            }
            s += __shfl_xor(s, 1);
            s += __shfl_xor(s, 2);
            s += __shfl_xor(s, 4);
            s += __shfl_xor(s, 8);
            if (ln == 0)
                loss[(size_t)b * NN + row] = 0.2f * sqrtf(s) + comb[row];
        }
    }
}

extern "C" void kernel_launch(void* const* d_in, const int* in_sizes, int n_in,
                              void* d_out, int out_size, void* d_ws, size_t ws_size,
                              hipStream_t stream) {
    const float* X   = (const float*)d_in[0];   // [B][N][D] f32
    const float* r   = (const float*)d_in[1];   // [D][D] f32
    const float* inc = (const float*)d_in[2];   // [N][N-1] f32
    float* out      = (float*)d_out;
    float* out_loss = out;                       // [B][N]
    float* out_inc  = out + (size_t)BB * NN;     // [N][N]

    float* comb = (float*)d_ws;                  // 16 KiB only

    hipLaunchKernelGGL(build_kernel, dim3(NN), dim3(256), 0, stream,
                       inc, out_inc, comb);
    hipLaunchKernelGGL(gemm_loss_kernel, dim3(NN / BM, BB / 2), dim3(256), 0, stream,
                       out_inc, X, r, comb, out_loss);
}

// Round 4
// 195.207 us; speedup vs baseline: 1.3868x; 1.3868x over previous
//
#include <hip/hip_runtime.h>
#include <hip/hip_bf16.h>

#define BB 16
#define NN 4096
#define DD 64
#define NM1 4095

typedef __bf16 bf16x8 __attribute__((ext_vector_type(8)));
typedef float f32x4 __attribute__((ext_vector_type(4)));

typedef __attribute__((address_space(1))) const void gas_void;
typedef __attribute__((address_space(3))) void las_void;

// ws layout:
//   [0]                  float mx[4096]          (16 KB)  -- zeroed via memsetAsync
//   [16384]              float ss[4096]          (16 KB)  -- zeroed via memsetAsync
//   [32768]              __bf16 XT[16][64][4096] ( 8 MiB)
//   [32768 + 8 MiB]      __bf16 A16[4096][4096]  (32 MiB)

// ---------------------------------------------------------------------------
// Kernel 1: flat scatter build. j-major: lane-consecutive loads AND stores.
//   out_inc[i*4096 + c + (c>=i)] = w  (f32 and bf16 copies); diag done by xt.
//   Per-row l1 (max) / l2 (sumsq) partials via wave reduce + global atomics.
// ---------------------------------------------------------------------------
__global__ __launch_bounds__(256) void build_kernel(
    const float* __restrict__ inc, float* __restrict__ out_inc,
    __bf16* __restrict__ A16, float* __restrict__ mxa, float* __restrict__ ssa)
{
    int t = threadIdx.x;
    int base = blockIdx.x << 12;                 // 4096 elems per block
    int rA = (int)((unsigned)base / NM1);        // block spans rows {rA, rA+1}
    float pm0 = 0.f, ps0 = 0.f, pm1 = 0.f, ps1 = 0.f;
    #pragma unroll
    for (int j = 0; j < 16; ++j) {
        int f = base + j * 256 + t;              // < 2^24, exact coverage
        int i = (int)((unsigned)f / NM1);
        int c = f - i * NM1;
        float x = inc[f];
        float w = x > 0.01f ? x : 0.f;
        int dst = f + i + (c >= i);              // i*4096 + c + (c>=i)
        out_inc[dst] = w;
        A16[dst] = (__bf16)w;
        if (i == rA) { pm0 = fmaxf(pm0, w); ps0 += w * w; }
        else         { pm1 = fmaxf(pm1, w); ps1 += w * w; }
    }
    #pragma unroll
    for (int off = 32; off; off >>= 1) {
        pm0 = fmaxf(pm0, __shfl_down(pm0, off));
        ps0 += __shfl_down(ps0, off);
        pm1 = fmaxf(pm1, __shfl_down(pm1, off));
        ps1 += __shfl_down(ps1, off);
    }
    __shared__ float sm0[4], sq0[4], sm1[4], sq1[4];
    int wid = t >> 6;
    if ((t & 63) == 0) { sm0[wid] = pm0; sq0[wid] = ps0; sm1[wid] = pm1; sq1[wid] = ps1; }
    __syncthreads();
    if (t == 0) {
        float m0v = fmaxf(fmaxf(sm0[0], sm0[1]), fmaxf(sm0[2], sm0[3]));
        float s0v = sq0[0] + sq0[1] + sq0[2] + sq0[3];
        float m1v = fmaxf(fmaxf(sm1[0], sm1[1]), fmaxf(sm1[2], sm1[3]));
        float s1v = sq1[0] + sq1[1] + sq1[2] + sq1[3];
        atomicMax((unsigned*)(mxa + rA), __float_as_uint(m0v));  // w >= 0
        atomicAdd(ssa + rA, s0v);
        int rB = rA + 1;
        if (rB < NN) {
            atomicMax((unsigned*)(mxa + rB), __float_as_uint(m1v));
            atomicAdd(ssa + rB, s1v);
        }
    }
}

// ---------------------------------------------------------------------------
// Kernel 2: XT[b][d][n] = (bf16)X[b][n][d]  (64x64 tiles via LDS) + diagonal
// ---------------------------------------------------------------------------
__global__ __launch_bounds__(256) void xt_kernel(
    const float* __restrict__ X, __bf16* __restrict__ XT,
    float* __restrict__ out_inc, __bf16* __restrict__ A16)
{
    __shared__ __bf16 tile[64 * 72];             // stride 72 elems = 144 B
    int t = threadIdx.x;
    int ntile = blockIdx.x, b = blockIdx.y;
    int n = t >> 2, q = t & 3;
    const float* src = X + ((size_t)b * NN + ntile * 64 + n) * DD + q * 16;
    #pragma unroll
    for (int v = 0; v < 4; ++v) {
        f32x4 u = *(const f32x4*)(src + v * 4);
        #pragma unroll
        for (int j = 0; j < 4; ++j) {
            int d = q * 16 + v * 4 + j;
            tile[d * 72 + n] = (__bf16)u[j];
        }
    }
    __syncthreads();
    int d = t >> 2;
    __bf16* dst = XT + ((size_t)b * DD + d) * NN + ntile * 64 + q * 16;
    *(bf16x8*)dst       = *(bf16x8*)&tile[d * 72 + q * 16];
    *(bf16x8*)(dst + 8) = *(bf16x8*)&tile[d * 72 + q * 16 + 8];
    if (b == 0 && t < 64) {                      // diagonal of W + I
        int r = ntile * 64 + t;
        out_inc[(size_t)r * NN + r] = 1.0f;
        A16[(size_t)r * NN + r] = (__bf16)1.0f;
    }
}

// ---------------------------------------------------------------------------
// Kernel 3: acc = A16 @ X[b] via MFMA (global_load_lds staging, XOR-swizzled
//   octets), fused xp = X[b]rows @ (r+I), loss epilogue.
//   grid (64, 16): m-tile x batch. 256 thr / 4 waves; wave = 32x32 quadrant
//   (rows (w&1)*32, cols (w>>1)*32). Same-m blocks share A via same XCD.
// ---------------------------------------------------------------------------
__global__ __launch_bounds__(256) void gemm_loss_kernel(
    const __bf16* __restrict__ A16, const __bf16* __restrict__ XT,
    const float* __restrict__ X, const float* __restrict__ rproj,
    const float* __restrict__ mxa, const float* __restrict__ ssa,
    float* __restrict__ loss)
{
    __shared__ __bf16 As[64 * 64];               // 8 KB, rows 128 B, swizzled
    __shared__ __bf16 Xs[64 * 64];               // 8 KB
    __shared__ float sred[64][2];

    int t = threadIdx.x;
    int wave = t >> 6, lane = t & 63;
    int quad = lane >> 4, ln = lane & 15;
    int m0 = blockIdx.x * 64;
    int b  = blockIdx.y;
    int mrow0 = (wave & 1) * 32;
    int ncol0 = (wave >> 1) * 32;
    int sr = lane >> 3;                          // staging row-in-group
    int so = lane & 7;                           // staging lds octet

    const __bf16* Abase = A16 + (size_t)m0 * NN;
    const __bf16* Xbase = XT + (size_t)b * DD * NN;

    f32x4 acc[2][2];
    f32x4 zero = {0.f, 0.f, 0.f, 0.f};
    #pragma unroll
    for (int mt = 0; mt < 2; ++mt)
        #pragma unroll
        for (int nt = 0; nt < 2; ++nt) acc[mt][nt] = zero;

    for (int kt = 0; kt < NN / 64; ++kt) {
        int k0 = kt * 64;
        #pragma unroll
        for (int p = 0; p < 2; ++p) {
            int r0 = p * 32 + wave * 8;          // wave-uniform
            int r  = r0 + sr;
            int og = so ^ (r & 7);               // LDS[r][o] = G[r][o^(r&7)]
            __builtin_amdgcn_global_load_lds(
                (gas_void*)(Abase + (size_t)r * NN + k0 + og * 8),
                (las_void*)(As + r0 * 64), 16, 0, 0);
            __builtin_amdgcn_global_load_lds(
                (gas_void*)(Xbase + (size_t)r * NN + k0 + og * 8),
                (las_void*)(Xs + r0 * 64), 16, 0, 0);
        }
        __syncthreads();
        #pragma unroll
        for (int kk = 0; kk < 64; kk += 32) {
            int oc = (kk >> 3) + quad;
            bf16x8 af[2], bfr[2];
            #pragma unroll
            for (int mt = 0; mt < 2; ++mt) {
                int r = mrow0 + mt * 16 + ln;
                af[mt] = *(const bf16x8*)&As[r * 64 + ((oc ^ (r & 7)) << 3)];
            }
            #pragma unroll
            for (int nt = 0; nt < 2; ++nt) {
                int n = ncol0 + nt * 16 + ln;
                bfr[nt] = *(const bf16x8*)&Xs[n * 64 + ((oc ^ (n & 7)) << 3)];
            }
            #pragma unroll
            for (int mt = 0; mt < 2; ++mt)
                #pragma unroll
                for (int nt = 0; nt < 2; ++nt)
                    acc[mt][nt] = __builtin_amdgcn_mfma_f32_16x16x32_bf16(
                        af[mt], bfr[nt], acc[mt][nt], 0, 0, 0);
        }
        __syncthreads();
    }

    // ---- phase 2: xp = X[b][m0..m0+63][:] @ (r+I), same layout as acc ----
    {
        int rr = t >> 2, q = t & 3;
        const float* xs = X + ((size_t)b * NN + m0 + rr) * DD + q * 16;
        #pragma unroll
        for (int v = 0; v < 2; ++v) {
            f32x4 u0 = *(const f32x4*)(xs + v * 8);
            f32x4 u1 = *(const f32x4*)(xs + v * 8 + 4);
            bf16x8 w;
            #pragma unroll
            for (int j = 0; j < 4; ++j) { w[j] = (__bf16)u0[j]; w[j + 4] = (__bf16)u1[j]; }
            int o = (q * 2 + v) ^ (rr & 7);
            *(bf16x8*)&As[rr * 64 + o * 8] = w;  // XA swizzled like main A
        }
        const float* rs = rproj + (size_t)rr * DD + q * 16;   // row e = rr
        #pragma unroll
        for (int v = 0; v < 4; ++v) {
            f32x4 u = *(const f32x4*)(rs + v * 4);
            #pragma unroll
            for (int j = 0; j < 4; ++j) {
                int d = q * 16 + v * 4 + j;
                float val = u[j] + (d == rr ? 1.0f : 0.0f);   // r + I
                // Bs[n=d][e]: octet (e>>3) swizzled by (d&7)
                Xs[d * 64 + (((rr >> 3) ^ (d & 7)) << 3) + (rr & 7)] = (__bf16)val;
            }
        }
    }
    __syncthreads();

    f32x4 xp[2][2];
    #pragma unroll
    for (int mt = 0; mt < 2; ++mt)
        #pragma unroll
        for (int nt = 0; nt < 2; ++nt) xp[mt][nt] = zero;
    #pragma unroll
    for (int kk = 0; kk < DD; kk += 32) {
        int oc = (kk >> 3) + quad;
        bf16x8 af[2], bfr[2];
        #pragma unroll
        for (int mt = 0; mt < 2; ++mt) {
            int r = mrow0 + mt * 16 + ln;
            af[mt] = *(const bf16x8*)&As[r * 64 + ((oc ^ (r & 7)) << 3)];
        }
        #pragma unroll
        for (int nt = 0; nt < 2; ++nt) {
            int n = ncol0 + nt * 16 + ln;
            bfr[nt] = *(const bf16x8*)&Xs[n * 64 + ((oc ^ (n & 7)) << 3)];
        }
        #pragma unroll
        for (int mt = 0; mt < 2; ++mt)
            #pragma unroll
            for (int nt = 0; nt < 2; ++nt)
                xp[mt][nt] = __builtin_amdgcn_mfma_f32_16x16x32_bf16(
                    af[mt], bfr[nt], xp[mt][nt], 0, 0, 0);
    }

    // ---- epilogue: C/D layout col=lane&15, row=quad*4+reg ----
    #pragma unroll
    for (int mt = 0; mt < 2; ++mt) {
        #pragma unroll
        for (int rg = 0; rg < 4; ++rg) {
            float s = 0.f;
            #pragma unroll
            for (int nt = 0; nt < 2; ++nt) {
                float df = xp[mt][nt][rg] - acc[mt][nt][rg];
                s += df * df;
            }
            s += __shfl_xor(s, 1);
            s += __shfl_xor(s, 2);
            s += __shfl_xor(s, 4);
            s += __shfl_xor(s, 8);
            if (ln == 0) sred[mrow0 + mt * 16 + quad * 4 + rg][wave >> 1] = s;
        }
    }
    __syncthreads();
    if (t < 64) {
        float s = sred[t][0] + sred[t][1];
        int row = m0 + t;
        loss[(size_t)b * NN + row] =
            0.2f * sqrtf(s) + mxa[row] + 0.001f * sqrtf(ssa[row]);
    }
}

extern "C" void kernel_launch(void* const* d_in, const int* in_sizes, int n_in,
                              void* d_out, int out_size, void* d_ws, size_t ws_size,
                              hipStream_t stream) {
    const float* X   = (const float*)d_in[0];   // [B][N][D] f32
    const float* r   = (const float*)d_in[1];   // [D][D] f32
    const float* inc = (const float*)d_in[2];   // [N][N-1] f32
    float* out      = (float*)d_out;
    float* out_loss = out;                       // [B][N]
    float* out_inc  = out + (size_t)BB * NN;     // [N][N]

    char* ws = (char*)d_ws;
    float*  mxa = (float*)ws;                               // 16 KB
    float*  ssa = (float*)(ws + 16384);                     // 16 KB
    __bf16* XT  = (__bf16*)(ws + 32768);                    //  8 MiB
    __bf16* A16 = (__bf16*)(ws + 32768 + (size_t)8 * 1024 * 1024);  // 32 MiB

    hipMemsetAsync(mxa, 0, 32768, stream);      // zero mx/ss accumulators

    hipLaunchKernelGGL(build_kernel, dim3(NM1), dim3(256), 0, stream,
                       inc, out_inc, A16, mxa, ssa);
    hipLaunchKernelGGL(xt_kernel, dim3(NN / 64, BB), dim3(256), 0, stream,
                       X, XT, out_inc, A16);
    hipLaunchKernelGGL(gemm_loss_kernel, dim3(NN / 64, BB), dim3(256), 0, stream,
                       A16, XT, X, r, mxa, ssa, out_loss);
}